// Round 2
// baseline (255.438 us; speedup 1.0000x reference)
//
#include <hip/hip_runtime.h>
#include <hip/hip_bf16.h>
#include <math.h>

#define DIM   768
#define CA    192
#define NTOK  25216   // 197*128

typedef __attribute__((ext_vector_type(8))) short short8;
typedef __attribute__((ext_vector_type(4))) float f32x4;

static __device__ __forceinline__ short f2bf(float f) {
    union { __hip_bfloat16 b; short s; } u;
    u.b = __float2bfloat16(f);
    return u.s;
}
static __device__ __forceinline__ float gelu_exact(float x) {
    return 0.5f * x * (1.0f + erff(x * 0.70710678118654752440f));
}

// ---------------------------------------------------------------------------
// Prep: w1 (768,192) -> w1T (192,768) bf16; w2 (192,768) -> w2T (768,192) bf16
// ---------------------------------------------------------------------------
__global__ void prep_kernel(const float* __restrict__ w1, const float* __restrict__ w2,
                            short* __restrict__ w1T, short* __restrict__ w2T) {
    int idx = blockIdx.x * 256 + threadIdx.x;
    if (idx < CA * DIM) {
        int n = idx / DIM, k = idx - n * DIM;
        w1T[idx] = f2bf(w1[k * CA + n]);
        int n2 = idx / CA, k2 = idx - n2 * CA;
        w2T[idx] = f2bf(w2[k2 * DIM + n2]);
    }
}

// ---------------------------------------------------------------------------
// Fused GEMM1 + temporal mix + gelu -> g (bf16).
// LDS-FREE: operands are cache-resident (w1T 288KB L2-hot, x L3-hot), so each
// lane loads its MFMA fragment straight from global memory:
//   A frag: x row (R0+wm*32+i2*16+lm), k-chunk lg*8  (2x f32x4 -> cvt bf16)
//   B frag: w1T row (n0+wn*48+j*16+lm), k-chunk lg*8 (1x b128)
// No barriers, no vmcnt(0) drains -> latency hidden by TLP (4 waves/SIMD via
// launch_bounds cap) + full unroll (24 iters, offsets fold to immediates)
// with explicit 1-deep register prefetch. Last iter peeled (no prefetch).
// Grid 784 = 196 l * 2 halfM * 2 halfN. 4 waves 2m x 2n, wave tile 32x48.
// Epilogue: res[b,c] = cb + (1/28)*sum_t coef[t,c]*h[t]; sum via shfl_xor 16.
// ---------------------------------------------------------------------------
__global__ __launch_bounds__(256, 4) void gemm1_fused(
        const float* __restrict__ x, const short* __restrict__ w1T,
        const float* __restrict__ b1, const float* __restrict__ conv_w,
        const float* __restrict__ conv_b, short* __restrict__ gq) {
    const int tid = threadIdx.x;
    const int bx  = blockIdx.x;
    const int l   = (bx >> 2) + 1;
    const int hm  = (bx >> 1) & 1;
    const int n0  = (bx & 1) * 96;
    const int R0  = l * 128 + hm * 64;

    const int wave = tid >> 6, lane = tid & 63;
    const int wm = wave >> 1, wn = wave & 1;
    const int lm = lane & 15, lg = lane >> 4;

    // per-lane fragment base pointers
    const float* aBase0 = x + (size_t)(R0 + wm * 32 + lm) * DIM + lg * 8;
    const float* aBase1 = aBase0 + (size_t)16 * DIM;
    const short* bBase  = w1T + (size_t)(n0 + wn * 48 + lm) * DIM + lg * 8;

    f32x4 acc[2][3] = {};

    // 1-deep software pipeline, fully unrolled (all offsets become immediates)
    f32x4 pa[2][2];
    short8 pb[3];
    pa[0][0] = *(const f32x4*)(aBase0);
    pa[0][1] = *(const f32x4*)(aBase0 + 4);
    pa[1][0] = *(const f32x4*)(aBase1);
    pa[1][1] = *(const f32x4*)(aBase1 + 4);
    pb[0] = *(const short8*)(bBase);
    pb[1] = *(const short8*)(bBase + 16 * DIM);
    pb[2] = *(const short8*)(bBase + 32 * DIM);

    #pragma unroll
    for (int i = 0; i < 23; i++) {
        const int kn = (i + 1) * 32;
        f32x4 na[2][2];
        short8 nb[3];
        na[0][0] = *(const f32x4*)(aBase0 + kn);
        na[0][1] = *(const f32x4*)(aBase0 + kn + 4);
        na[1][0] = *(const f32x4*)(aBase1 + kn);
        na[1][1] = *(const f32x4*)(aBase1 + kn + 4);
        nb[0] = *(const short8*)(bBase + kn);
        nb[1] = *(const short8*)(bBase + 16 * DIM + kn);
        nb[2] = *(const short8*)(bBase + 32 * DIM + kn);

        short8 af[2];
        #pragma unroll
        for (int e = 0; e < 4; e++) {
            af[0][e]     = f2bf(pa[0][0][e]);
            af[0][4 + e] = f2bf(pa[0][1][e]);
            af[1][e]     = f2bf(pa[1][0][e]);
            af[1][4 + e] = f2bf(pa[1][1][e]);
        }
        #pragma unroll
        for (int i2 = 0; i2 < 2; i2++)
            #pragma unroll
            for (int j = 0; j < 3; j++)
                acc[i2][j] = __builtin_amdgcn_mfma_f32_16x16x32_bf16(af[i2], pb[j], acc[i2][j], 0, 0, 0);

        pa[0][0] = na[0][0]; pa[0][1] = na[0][1];
        pa[1][0] = na[1][0]; pa[1][1] = na[1][1];
        pb[0] = nb[0]; pb[1] = nb[1]; pb[2] = nb[2];
    }
    // peeled last iteration (no prefetch)
    {
        short8 af[2];
        #pragma unroll
        for (int e = 0; e < 4; e++) {
            af[0][e]     = f2bf(pa[0][0][e]);
            af[0][4 + e] = f2bf(pa[0][1][e]);
            af[1][e]     = f2bf(pa[1][0][e]);
            af[1][4 + e] = f2bf(pa[1][1][e]);
        }
        #pragma unroll
        for (int i2 = 0; i2 < 2; i2++)
            #pragma unroll
            for (int j = 0; j < 3; j++)
                acc[i2][j] = __builtin_amdgcn_mfma_f32_16x16x32_bf16(af[i2], pb[j], acc[i2][j], 0, 0, 0);
    }

    // Epilogue: bias, temporal res via shfl, gelu, bf16 store. h never hits HBM.
    const int g1 = lg & 1;
    #pragma unroll
    for (int j = 0; j < 3; j++) {
        const int c = n0 + wn * 48 + j * 16 + lm;
        const float b1c = b1[c];
        const float cw0 = conv_w[c * 3 + 0];
        const float cw1 = conv_w[c * 3 + 1];
        const float cw2 = conv_w[c * 3 + 2];
        const float cb  = conv_b[c];
        #pragma unroll
        for (int i2 = 0; i2 < 2; i2++) {
            float hv[4];
            #pragma unroll
            for (int r = 0; r < 4; r++) hv[r] = acc[i2][j][r] + b1c;
            float partial = 0.f;
            #pragma unroll
            for (int r = 0; r < 4; r++) {
                const int t = g1 * 4 + r;
                const float tf = (float)t;
                float coef = tf * cw1 - (7.0f - tf);
                if (t <= 6) coef += (tf + 1.0f) * cw0;
                if (t >= 1) coef += (tf - 1.0f) * cw2;
                partial += coef * hv[r];
            }
            const float full = partial + __shfl_xor(partial, 16);
            const float res = cb + full * (1.0f / 28.0f);
            const int row = R0 + wm * 32 + i2 * 16 + lg * 4;
            #pragma unroll
            for (int r = 0; r < 4; r++)
                gq[(size_t)(row + r) * CA + c] = f2bf(gelu_exact(hv[r] + res));
            if (l == 1) {                       // out token 0 = gelu(h[l=1]) (no res)
                const int bt = row - 128;
                #pragma unroll
                for (int r = 0; r < 4; r++)
                    gq[(size_t)(bt + r) * CA + c] = f2bf(gelu_exact(hv[r]));
            }
        }
    }
}

// ---------------------------------------------------------------------------
// GEMM2: out = x + g @ w2 + b2. M=25216, K=192, N=768.
// LDS-FREE: g (9.7MB) and w2T (288KB) are L2-resident; fragments loaded
// per-lane straight from global (1x b128 each). No barriers. K fully
// unrolled (6 subtiles of 32), 1-deep register prefetch, last iter peeled.
// BM=64, BN=128 -> grid (394, 6). 4 waves 2m x 2n, wave tile 32x64.
// ---------------------------------------------------------------------------
__global__ __launch_bounds__(256, 4) void gemm2_kernel(
        const short* __restrict__ gq, const short* __restrict__ w2T,
        const float* __restrict__ b2, const float* __restrict__ x,
        float* __restrict__ out) {
    const int tid = threadIdx.x;
    const int m0 = blockIdx.x * 64;
    const int n0 = blockIdx.y * 128;
    const int wave = tid >> 6, lane = tid & 63;
    const int wm = wave >> 1, wn = wave & 1;
    const int lm = lane & 15, lg = lane >> 4;

    const short* aBase = gq  + (size_t)(m0 + wm * 32 + lm) * CA + lg * 8;
    const short* bBase = w2T + (size_t)(n0 + wn * 64 + lm) * CA + lg * 8;

    f32x4 acc[2][4] = {};

    short8 pa[2], pb[4];
    pa[0] = *(const short8*)(aBase);
    pa[1] = *(const short8*)(aBase + 16 * CA);
    pb[0] = *(const short8*)(bBase);
    pb[1] = *(const short8*)(bBase + 16 * CA);
    pb[2] = *(const short8*)(bBase + 32 * CA);
    pb[3] = *(const short8*)(bBase + 48 * CA);

    #pragma unroll
    for (int i = 0; i < 5; i++) {
        const int kn = (i + 1) * 32;
        short8 na[2], nb[4];
        na[0] = *(const short8*)(aBase + kn);
        na[1] = *(const short8*)(aBase + 16 * CA + kn);
        nb[0] = *(const short8*)(bBase + kn);
        nb[1] = *(const short8*)(bBase + 16 * CA + kn);
        nb[2] = *(const short8*)(bBase + 32 * CA + kn);
        nb[3] = *(const short8*)(bBase + 48 * CA + kn);

        #pragma unroll
        for (int i2 = 0; i2 < 2; i2++)
            #pragma unroll
            for (int j = 0; j < 4; j++)
                acc[i2][j] = __builtin_amdgcn_mfma_f32_16x16x32_bf16(pa[i2], pb[j], acc[i2][j], 0, 0, 0);

        pa[0] = na[0]; pa[1] = na[1];
        pb[0] = nb[0]; pb[1] = nb[1]; pb[2] = nb[2]; pb[3] = nb[3];
    }
    // peeled last iteration
    #pragma unroll
    for (int i2 = 0; i2 < 2; i2++)
        #pragma unroll
        for (int j = 0; j < 4; j++)
            acc[i2][j] = __builtin_amdgcn_mfma_f32_16x16x32_bf16(pa[i2], pb[j], acc[i2][j], 0, 0, 0);

    #pragma unroll
    for (int i2 = 0; i2 < 2; i2++) {
        const int row0 = m0 + wm * 32 + i2 * 16 + lg * 4;
        #pragma unroll
        for (int j = 0; j < 4; j++) {
            const int col = n0 + wn * 64 + j * 16 + lm;
            const float bias = b2[col];
            #pragma unroll
            for (int r = 0; r < 4; r++) {
                const size_t idx = (size_t)(row0 + r) * DIM + col;
                out[idx] = acc[i2][j][r] + x[idx] + bias;
            }
        }
    }
}

// ---------------------------------------------------------------------------
extern "C" void kernel_launch(void* const* d_in, const int* in_sizes, int n_in,
                              void* d_out, int out_size, void* d_ws, size_t ws_size,
                              hipStream_t stream) {
    (void)in_sizes; (void)n_in; (void)out_size; (void)ws_size;
    const float* x      = (const float*)d_in[0];
    const float* w1     = (const float*)d_in[1];
    const float* b1     = (const float*)d_in[2];
    const float* conv_w = (const float*)d_in[3];
    const float* conv_b = (const float*)d_in[4];
    const float* w2     = (const float*)d_in[5];
    const float* b2     = (const float*)d_in[6];
    float* out = (float*)d_out;

    char* ws = (char*)d_ws;
    short* g   = (short*)ws;                           // 25216*192*2 = 9,682,944 B
    short* w1T = (short*)(ws + 9682944);               // 294,912 B
    short* w2T = (short*)(ws + 9682944 + 294912);      // 294,912 B

    prep_kernel<<<(CA * DIM + 255) / 256, 256, 0, stream>>>(w1, w2, w1T, w2T);
    gemm1_fused<<<784, 256, 0, stream>>>(x, w1T, b1, conv_w, conv_b, g);
    gemm2_kernel<<<dim3(394, 6), 256, 0, stream>>>(g, w2T, b2, x, out);
}

// Round 3
// 201.863 us; speedup vs baseline: 1.2654x; 1.2654x over previous
//
#include <hip/hip_runtime.h>
#include <hip/hip_bf16.h>
#include <math.h>

#define DIM   768
#define CA    192
#define NTOK  25216   // 197*128

typedef __attribute__((ext_vector_type(8))) short short8;
typedef __attribute__((ext_vector_type(4))) float f32x4;

static __device__ __forceinline__ short f2bf(float f) {
    union { __hip_bfloat16 b; short s; } u;
    u.b = __float2bfloat16(f);
    return u.s;
}
static __device__ __forceinline__ float gelu_exact(float x) {
    return 0.5f * x * (1.0f + erff(x * 0.70710678118654752440f));
}
// async global->LDS DMA, 16B per lane; lds base must be wave-uniform.
static __device__ __forceinline__ void ld16(void* lds, const void* gsrc) {
    __builtin_amdgcn_global_load_lds((const __attribute__((address_space(1))) void*)gsrc,
                                     (__attribute__((address_space(3))) void*)lds, 16, 0, 0);
}

// ---------------------------------------------------------------------------
// Prep: w1 (768,192) -> w1T (192,768) bf16; w2 (192,768) -> w2T (768,192) bf16
// ---------------------------------------------------------------------------
__global__ void prep_kernel(const float* __restrict__ w1, const float* __restrict__ w2,
                            short* __restrict__ w1T, short* __restrict__ w2T) {
    int idx = blockIdx.x * 256 + threadIdx.x;
    if (idx < CA * DIM) {
        int n = idx / DIM, k = idx - n * DIM;
        w1T[idx] = f2bf(w1[k * CA + n]);
        int n2 = idx / CA, k2 = idx - n2 * CA;
        w2T[idx] = f2bf(w2[k2 * DIM + n2]);
    }
}

// ---------------------------------------------------------------------------
// xcvt: x f32 -> bf16, stored in d_out's first 38.7MB (overwritten by gemm2).
// 19,365,888 elems / 8 per thread = 2,420,736 threads = 9456 blocks exactly.
// ---------------------------------------------------------------------------
__global__ __launch_bounds__(256) void xcvt_kernel(const float* __restrict__ x,
                                                   short* __restrict__ xbf) {
    size_t i = ((size_t)blockIdx.x * 256 + threadIdx.x) * 8;
    f32x4 a = *(const f32x4*)(x + i);
    f32x4 b = *(const f32x4*)(x + i + 4);
    short8 o;
    #pragma unroll
    for (int e = 0; e < 4; e++) { o[e] = f2bf(a[e]); o[4 + e] = f2bf(b[e]); }
    *(short8*)(xbf + i) = o;
}

// ---------------------------------------------------------------------------
// Fused GEMM1 + temporal mix + gelu -> g (bf16).
// Full-DMA staging (A from xbf, B from w1T), BK=64, 12 iters.
// 3 LDS buffers (20KB each: A 8KB + B 12KB), 2-iteration prefetch lead,
// counted s_waitcnt vmcnt(5) + raw s_barrier: ONE barrier per iter, vmcnt
// never drained to 0 in the main loop (T3+T4 pattern).
// Chunk swizzle both-sides (rule 21): slot = m*8 + (q ^ (m&7)) on the DMA
// source; ds_read applies the same XOR -> 2-way bank access (free).
// Per wave per iter: 5 DMA issues, 10 ds_read_b128, 12 MFMA.
// Safety: readers finish ds_read before their own barrier (asm memory
// clobber); stagers write the 2-ahead buffer only after that barrier.
// Grid 784 = 196 l * 2 halfM * 2 halfN. 4 waves 2m x 2n, wave tile 32x48.
// Epilogue: res[b,c] = cb + (1/28)*sum_t coef[t,c]*h[t]; sum via shfl_xor 16.
// ---------------------------------------------------------------------------
__global__ __launch_bounds__(256, 2) void gemm1_fused(
        const short* __restrict__ xbf, const short* __restrict__ w1T,
        const float* __restrict__ b1, const float* __restrict__ conv_w,
        const float* __restrict__ conv_b, short* __restrict__ gq) {
    __shared__ __align__(16) short lds[3][10240];   // per stage: A[0..4095], B[4096..10239]

    const int tid = threadIdx.x;
    const int bx  = blockIdx.x;
    const int l   = (bx >> 2) + 1;
    const int hm  = (bx >> 1) & 1;
    const int n0  = (bx & 1) * 96;
    const int R0  = l * 128 + hm * 64;

    const int wave = tid >> 6, lane = tid & 63;
    const int wm = wave >> 1, wn = wave & 1;
    const int lm = lane & 15, lg = lane >> 4;

    // 20 DMA instrs per stage (A:8, B:12), 5 per wave. s5 = wave*5+j.
    const short* src[5];
    int loff[5];
    #pragma unroll
    for (int j = 0; j < 5; j++) {
        int s5 = wave * 5 + j;
        if (s5 < 8) {            // A region: slot = m*8 + (q ^ (m&7)), m in [0,64)
            int idx = s5 * 64 + lane;
            int m = idx >> 3, q = (idx & 7) ^ (m & 7);
            src[j]  = xbf + (size_t)(R0 + m) * DIM + q * 8;
            loff[j] = s5 * 512;
        } else {                 // B region: m in [0,96)
            int idx = (s5 - 8) * 64 + lane;
            int m = idx >> 3, q = (idx & 7) ^ (m & 7);
            src[j]  = w1T + (size_t)(n0 + m) * DIM + q * 8;
            loff[j] = 4096 + (s5 - 8) * 512;
        }
    }

    f32x4 acc[2][3] = {};

    auto STAGE = [&](int t, int buf) {
        #pragma unroll
        for (int j = 0; j < 5; j++)
            ld16(&lds[buf][loff[j]], src[j] + t * 64);
    };

    STAGE(0, 0);
    STAGE(1, 1);

    #pragma unroll
    for (int t = 0; t < 12; t++) {
        // retire stage t (issued 2 iters ago); keep the 5 ops of stage t+1 in flight
        if (t < 11) asm volatile("s_waitcnt vmcnt(5)" ::: "memory");
        else        asm volatile("s_waitcnt vmcnt(0)" ::: "memory");
        __builtin_amdgcn_s_barrier();
        if (t < 10) STAGE(t + 2, (t + 2) % 3);

        const short* A = &lds[t % 3][0];
        const short* B = &lds[t % 3][4096];
        short8 af[2][2], bf[3][2];
        #pragma unroll
        for (int i2 = 0; i2 < 2; i2++) {
            int r = wm * 32 + i2 * 16 + lm;
            #pragma unroll
            for (int ks = 0; ks < 2; ks++) {
                int c = ks * 4 + lg;
                af[i2][ks] = *(const short8*)&A[(r * 8 + (c ^ (r & 7))) * 8];
            }
        }
        #pragma unroll
        for (int j = 0; j < 3; j++) {
            int rB = wn * 48 + j * 16 + lm;
            #pragma unroll
            for (int ks = 0; ks < 2; ks++) {
                int c = ks * 4 + lg;
                bf[j][ks] = *(const short8*)&B[(rB * 8 + (c ^ (rB & 7))) * 8];
            }
        }
        #pragma unroll
        for (int ks = 0; ks < 2; ks++)
            #pragma unroll
            for (int i2 = 0; i2 < 2; i2++)
                #pragma unroll
                for (int j = 0; j < 3; j++)
                    acc[i2][j] = __builtin_amdgcn_mfma_f32_16x16x32_bf16(af[i2][ks], bf[j][ks], acc[i2][j], 0, 0, 0);
    }

    // Epilogue (verified in round-0): bias, temporal res via shfl, gelu, bf16 store.
    const int g1 = lg & 1;
    #pragma unroll
    for (int j = 0; j < 3; j++) {
        const int c = n0 + wn * 48 + j * 16 + lm;
        const float b1c = b1[c];
        const float cw0 = conv_w[c * 3 + 0];
        const float cw1 = conv_w[c * 3 + 1];
        const float cw2 = conv_w[c * 3 + 2];
        const float cb  = conv_b[c];
        #pragma unroll
        for (int i2 = 0; i2 < 2; i2++) {
            float hv[4];
            #pragma unroll
            for (int r = 0; r < 4; r++) hv[r] = acc[i2][j][r] + b1c;
            float partial = 0.f;
            #pragma unroll
            for (int r = 0; r < 4; r++) {
                const int t = g1 * 4 + r;
                const float tf = (float)t;
                float coef = tf * cw1 - (7.0f - tf);
                if (t <= 6) coef += (tf + 1.0f) * cw0;
                if (t >= 1) coef += (tf - 1.0f) * cw2;
                partial += coef * hv[r];
            }
            const float full = partial + __shfl_xor(partial, 16);
            const float res = cb + full * (1.0f / 28.0f);
            const int row = R0 + wm * 32 + i2 * 16 + lg * 4;
            #pragma unroll
            for (int r = 0; r < 4; r++)
                gq[(size_t)(row + r) * CA + c] = f2bf(gelu_exact(hv[r] + res));
            if (l == 1) {                       // out token 0 = gelu(h[l=1]) (no res)
                const int bt = row - 128;
                #pragma unroll
                for (int r = 0; r < 4; r++)
                    gq[(size_t)(bt + r) * CA + c] = f2bf(gelu_exact(hv[r]));
            }
        }
    }
}

// ---------------------------------------------------------------------------
// GEMM2: out = x + g @ w2 + b2. M=25216, K=192, N=768. BK=64 -> 3 iters.
// Full-DMA staging, 2 buffers (24KB each: A 8KB + B 16KB), 1-iter lead,
// vmcnt(0) + raw s_barrier once per iter (drain lands after a full compute
// phase, not right after issue). Same both-sides chunk swizzle.
// Per wave per iter: 6 DMA issues, 12 ds_read_b128, 16 MFMA.
// BM=64, BN=128 -> grid (394, 6). 4 waves 2m x 2n, wave tile 32x64.
// ---------------------------------------------------------------------------
__global__ __launch_bounds__(256, 2) void gemm2_kernel(
        const short* __restrict__ gq, const short* __restrict__ w2T,
        const float* __restrict__ b2, const float* __restrict__ x,
        float* __restrict__ out) {
    __shared__ __align__(16) short lds[2][12288];   // per stage: A[0..4095], B[4096..12287]

    const int tid = threadIdx.x;
    const int m0 = blockIdx.x * 64;
    const int n0 = blockIdx.y * 128;
    const int wave = tid >> 6, lane = tid & 63;
    const int wm = wave >> 1, wn = wave & 1;
    const int lm = lane & 15, lg = lane >> 4;

    // 24 DMA instrs per stage (A:8, B:16), 6 per wave. s6 = wave*6+j.
    const short* src[6];
    int loff[6];
    #pragma unroll
    for (int j = 0; j < 6; j++) {
        int s6 = wave * 6 + j;
        if (s6 < 8) {            // A region, m in [0,64)
            int idx = s6 * 64 + lane;
            int m = idx >> 3, q = (idx & 7) ^ (m & 7);
            src[j]  = gq + (size_t)(m0 + m) * CA + q * 8;
            loff[j] = s6 * 512;
        } else {                 // B region, m in [0,128)
            int idx = (s6 - 8) * 64 + lane;
            int m = idx >> 3, q = (idx & 7) ^ (m & 7);
            src[j]  = w2T + (size_t)(n0 + m) * CA + q * 8;
            loff[j] = 4096 + (s6 - 8) * 512;
        }
    }

    f32x4 acc[2][4] = {};

    auto STAGE = [&](int t, int buf) {
        #pragma unroll
        for (int j = 0; j < 6; j++)
            ld16(&lds[buf][loff[j]], src[j] + t * 64);
    };

    STAGE(0, 0);

    #pragma unroll
    for (int t = 0; t < 3; t++) {
        asm volatile("s_waitcnt vmcnt(0)" ::: "memory");
        __builtin_amdgcn_s_barrier();
        if (t < 2) STAGE(t + 1, (t + 1) & 1);

        const short* A = &lds[t & 1][0];
        const short* B = &lds[t & 1][4096];
        #pragma unroll
        for (int kk = 0; kk < 2; kk++) {
            const int c = kk * 4 + lg;
            short8 af[2], bf[4];
            #pragma unroll
            for (int i2 = 0; i2 < 2; i2++) {
                int r = wm * 32 + i2 * 16 + lm;
                af[i2] = *(const short8*)&A[(r * 8 + (c ^ (r & 7))) * 8];
            }
            #pragma unroll
            for (int j = 0; j < 4; j++) {
                int rB = wn * 64 + j * 16 + lm;
                bf[j] = *(const short8*)&B[(rB * 8 + (c ^ (rB & 7))) * 8];
            }
            #pragma unroll
            for (int i2 = 0; i2 < 2; i2++)
                #pragma unroll
                for (int j = 0; j < 4; j++)
                    acc[i2][j] = __builtin_amdgcn_mfma_f32_16x16x32_bf16(af[i2], bf[j], acc[i2][j], 0, 0, 0);
        }
    }

    #pragma unroll
    for (int i2 = 0; i2 < 2; i2++) {
        const int row0 = m0 + wm * 32 + i2 * 16 + lg * 4;
        #pragma unroll
        for (int j = 0; j < 4; j++) {
            const int col = n0 + wn * 64 + j * 16 + lm;
            const float bias = b2[col];
            #pragma unroll
            for (int r = 0; r < 4; r++) {
                const size_t idx = (size_t)(row0 + r) * DIM + col;
                out[idx] = acc[i2][j][r] + x[idx] + bias;
            }
        }
    }
}

// ---------------------------------------------------------------------------
extern "C" void kernel_launch(void* const* d_in, const int* in_sizes, int n_in,
                              void* d_out, int out_size, void* d_ws, size_t ws_size,
                              hipStream_t stream) {
    (void)in_sizes; (void)n_in; (void)out_size; (void)ws_size;
    const float* x      = (const float*)d_in[0];
    const float* w1     = (const float*)d_in[1];
    const float* b1     = (const float*)d_in[2];
    const float* conv_w = (const float*)d_in[3];
    const float* conv_b = (const float*)d_in[4];
    const float* w2     = (const float*)d_in[5];
    const float* b2     = (const float*)d_in[6];
    float* out = (float*)d_out;

    char* ws = (char*)d_ws;
    short* g   = (short*)ws;                           // 25216*192*2 = 9,682,944 B
    short* w1T = (short*)(ws + 9682944);               // 294,912 B
    short* w2T = (short*)(ws + 9682944 + 294912);      // 294,912 B
    short* xbf = (short*)out;                          // scratch: first 38.7MB of out,
                                                       // fully overwritten by gemm2

    prep_kernel<<<(CA * DIM + 255) / 256, 256, 0, stream>>>(w1, w2, w1T, w2T);
    xcvt_kernel<<<9456, 256, 0, stream>>>(x, xbf);
    gemm1_fused<<<784, 256, 0, stream>>>(xbf, w1T, b1, conv_w, conv_b, g);
    gemm2_kernel<<<dim3(394, 6), 256, 0, stream>>>(g, w2T, b2, x, out);
}

// Round 4
// 197.051 us; speedup vs baseline: 1.2963x; 1.0244x over previous
//
#include <hip/hip_runtime.h>
#include <hip/hip_bf16.h>
#include <math.h>

#define DIM   768
#define CA    192
#define NTOK  25216   // 197*128

typedef __attribute__((ext_vector_type(8))) short short8;
typedef __attribute__((ext_vector_type(4))) float f32x4;

static __device__ __forceinline__ short f2bf(float f) {
    union { __hip_bfloat16 b; short s; } u;
    u.b = __float2bfloat16(f);
    return u.s;
}
static __device__ __forceinline__ float gelu_exact(float x) {
    return 0.5f * x * (1.0f + erff(x * 0.70710678118654752440f));
}
// async global->LDS DMA, 16B per lane; lds base must be wave-uniform.
static __device__ __forceinline__ void ld16(void* lds, const void* gsrc) {
    __builtin_amdgcn_global_load_lds((const __attribute__((address_space(1))) void*)gsrc,
                                     (__attribute__((address_space(3))) void*)lds, 16, 0, 0);
}

// ---------------------------------------------------------------------------
// Prep: w1 (768,192) -> w1T (192,768) bf16; w2 (192,768) -> w2T (768,192) bf16
// ---------------------------------------------------------------------------
__global__ void prep_kernel(const float* __restrict__ w1, const float* __restrict__ w2,
                            short* __restrict__ w1T, short* __restrict__ w2T) {
    int idx = blockIdx.x * 256 + threadIdx.x;
    if (idx < CA * DIM) {
        int n = idx / DIM, k = idx - n * DIM;
        w1T[idx] = f2bf(w1[k * CA + n]);
        int n2 = idx / CA, k2 = idx - n2 * CA;
        w2T[idx] = f2bf(w2[k2 * DIM + n2]);
    }
}

// ---------------------------------------------------------------------------
// Fused GEMM1 + temporal mix + gelu -> g (bf16).
// B: 3-buffer global_load_lds pipeline, 2-iter lead, counted vmcnt(7), ONE
//    barrier per iter (T3+T4). 12 iters of BK=64.
// A: register-staged from f32 x (xcvt pass eliminated): each thread loads
//    64B of consecutive f32 (1-iter lead), cvt->bf16, ds_write_b128 into the
//    NEXT stage buffer with the same XOR chunk swizzle the readers use.
//    lgkmcnt(0) before each barrier publishes the writes.
// vmcnt accounting (per wave per iter): 3 B-DMA + 4 A-loads issued; at top of
// iter t the 7 newer ops are B(t+1)[3]+A(t+1)[4], so vmcnt(7) retires B(t).
// Compiler inserts its own precise vmcnt for the A-reg cvt use.
// Chunk swizzle both-sides: slot = m*8 + (q ^ (m&7)); ds_read same XOR.
// Grid 784 = 196 l * 2 halfM * 2 halfN. 4 waves 2m x 2n, wave tile 32x48.
// Epilogue: res[b,c] = cb + (1/28)*sum_t coef[t,c]*h[t]; sum via shfl_xor 16.
// ---------------------------------------------------------------------------
__global__ __launch_bounds__(256, 2) void gemm1_fused(
        const float* __restrict__ x, const short* __restrict__ w1T,
        const float* __restrict__ b1, const float* __restrict__ conv_w,
        const float* __restrict__ conv_b, short* __restrict__ gq) {
    __shared__ __align__(16) short lds[3][10240];   // per stage: A[0..4095], B[4096..10239]

    const int tid = threadIdx.x;
    const int bx  = blockIdx.x;
    const int l   = (bx >> 2) + 1;
    const int hm  = (bx >> 1) & 1;
    const int n0  = (bx & 1) * 96;
    const int R0  = l * 128 + hm * 64;

    const int wave = tid >> 6, lane = tid & 63;
    const int wm = wave >> 1, wn = wave & 1;
    const int lm = lane & 15, lg = lane >> 4;

    // B DMA: 12 chunk-instrs per stage, 3 per wave. slot = m*8 + (q ^ (m&7)).
    const short* bsrc[3];
    int bloff[3];
    #pragma unroll
    for (int j = 0; j < 3; j++) {
        int s3 = wave * 3 + j;
        int idx = s3 * 64 + lane;
        int m = idx >> 3, q = (idx & 7) ^ (m & 7);
        bsrc[j]  = w1T + (size_t)(n0 + m) * DIM + q * 8;
        bloff[j] = 4096 + s3 * 512;
    }

    // A reg-stage: thread owns row ar = tid>>2, 16 consecutive k at (tid&3)*16.
    const int ar  = tid >> 2;
    const int aq0 = (tid & 3) * 2;                  // two 8-elem chunks
    const float* xrow = x + (size_t)(R0 + ar) * DIM + aq0 * 8;

    f32x4 acc[2][3] = {};
    f32x4 a_regs[4];

    auto STAGE_B = [&](int t, int buf) {
        #pragma unroll
        for (int j = 0; j < 3; j++)
            ld16(&lds[buf][bloff[j]], bsrc[j] + t * 64);
    };
    auto WRITE_A = [&](int buf) {
        short8 lo, hi;
        #pragma unroll
        for (int e = 0; e < 4; e++) {
            lo[e] = f2bf(a_regs[0][e]); lo[4 + e] = f2bf(a_regs[1][e]);
            hi[e] = f2bf(a_regs[2][e]); hi[4 + e] = f2bf(a_regs[3][e]);
        }
        short* Ab = &lds[buf][0];
        *(short8*)&Ab[ar * 64 + ((aq0    ) ^ (ar & 7)) * 8] = lo;
        *(short8*)&Ab[ar * 64 + ((aq0 + 1) ^ (ar & 7)) * 8] = hi;
    };

    // prologue: A(0) regs; B(0),B(1) DMA; write A(0); A(1) regs
    #pragma unroll
    for (int e = 0; e < 4; e++) a_regs[e] = *(const f32x4*)(xrow + e * 4);
    STAGE_B(0, 0);
    STAGE_B(1, 1);
    WRITE_A(0);
    #pragma unroll
    for (int e = 0; e < 4; e++) a_regs[e] = *(const f32x4*)(xrow + 64 + e * 4);

    #pragma unroll
    for (int t = 0; t < 12; t++) {
        if (t < 11) asm volatile("s_waitcnt vmcnt(7) lgkmcnt(0)" ::: "memory");
        else        asm volatile("s_waitcnt vmcnt(0) lgkmcnt(0)" ::: "memory");
        __builtin_amdgcn_s_barrier();
        if (t < 10) STAGE_B(t + 2, (t + 2) % 3);

        const short* A = &lds[t % 3][0];
        const short* B = &lds[t % 3][4096];
        short8 af[2][2], bf[3][2];
        #pragma unroll
        for (int i2 = 0; i2 < 2; i2++) {
            int r = wm * 32 + i2 * 16 + lm;
            #pragma unroll
            for (int ks = 0; ks < 2; ks++) {
                int c = ks * 4 + lg;
                af[i2][ks] = *(const short8*)&A[(r * 8 + (c ^ (r & 7))) * 8];
            }
        }
        #pragma unroll
        for (int j = 0; j < 3; j++) {
            int rB = wn * 48 + j * 16 + lm;
            #pragma unroll
            for (int ks = 0; ks < 2; ks++) {
                int c = ks * 4 + lg;
                bf[j][ks] = *(const short8*)&B[(rB * 8 + (c ^ (rB & 7))) * 8];
            }
        }
        #pragma unroll
        for (int ks = 0; ks < 2; ks++)
            #pragma unroll
            for (int i2 = 0; i2 < 2; i2++)
                #pragma unroll
                for (int j = 0; j < 3; j++)
                    acc[i2][j] = __builtin_amdgcn_mfma_f32_16x16x32_bf16(af[i2][ks], bf[j][ks], acc[i2][j], 0, 0, 0);

        if (t < 11) {
            WRITE_A((t + 1) % 3);                   // A(t+1) from regs loaded at t-1
            if (t < 10) {
                const float* xn = xrow + (t + 2) * 64;
                #pragma unroll
                for (int e = 0; e < 4; e++) a_regs[e] = *(const f32x4*)(xn + e * 4);
            }
        }
    }

    // Epilogue (verified): bias, temporal res via shfl, gelu, bf16 store.
    const int g1 = lg & 1;
    #pragma unroll
    for (int j = 0; j < 3; j++) {
        const int c = n0 + wn * 48 + j * 16 + lm;
        const float b1c = b1[c];
        const float cw0 = conv_w[c * 3 + 0];
        const float cw1 = conv_w[c * 3 + 1];
        const float cw2 = conv_w[c * 3 + 2];
        const float cb  = conv_b[c];
        #pragma unroll
        for (int i2 = 0; i2 < 2; i2++) {
            float hv[4];
            #pragma unroll
            for (int r = 0; r < 4; r++) hv[r] = acc[i2][j][r] + b1c;
            float partial = 0.f;
            #pragma unroll
            for (int r = 0; r < 4; r++) {
                const int t = g1 * 4 + r;
                const float tf = (float)t;
                float coef = tf * cw1 - (7.0f - tf);
                if (t <= 6) coef += (tf + 1.0f) * cw0;
                if (t >= 1) coef += (tf - 1.0f) * cw2;
                partial += coef * hv[r];
            }
            const float full = partial + __shfl_xor(partial, 16);
            const float res = cb + full * (1.0f / 28.0f);
            const int row = R0 + wm * 32 + i2 * 16 + lg * 4;
            #pragma unroll
            for (int r = 0; r < 4; r++)
                gq[(size_t)(row + r) * CA + c] = f2bf(gelu_exact(hv[r] + res));
            if (l == 1) {                       // out token 0 = gelu(h[l=1]) (no res)
                const int bt = row - 128;
                #pragma unroll
                for (int r = 0; r < 4; r++)
                    gq[(size_t)(bt + r) * CA + c] = f2bf(gelu_exact(hv[r]));
            }
        }
    }
}

// ---------------------------------------------------------------------------
// GEMM2: out = x + g @ w2 + b2. M=25216, K=192, N=768. BK=64 -> 3 iters.
// Full-DMA staging, 2 buffers (24KB each: A 8KB + B 16KB), 1-iter lead,
// vmcnt(0) + raw s_barrier once per iter (the wait is for DMA issued a full
// compute phase earlier). Same both-sides chunk swizzle.
// BM=64, BN=128 -> grid (394, 6). 4 waves 2m x 2n, wave tile 32x64.
// ---------------------------------------------------------------------------
__global__ __launch_bounds__(256, 2) void gemm2_kernel(
        const short* __restrict__ gq, const short* __restrict__ w2T,
        const float* __restrict__ b2, const float* __restrict__ x,
        float* __restrict__ out) {
    __shared__ __align__(16) short lds[2][12288];   // per stage: A[0..4095], B[4096..12287]

    const int tid = threadIdx.x;
    const int m0 = blockIdx.x * 64;
    const int n0 = blockIdx.y * 128;
    const int wave = tid >> 6, lane = tid & 63;
    const int wm = wave >> 1, wn = wave & 1;
    const int lm = lane & 15, lg = lane >> 4;

    // 24 DMA instrs per stage (A:8, B:16), 6 per wave. s6 = wave*6+j.
    const short* src[6];
    int loff[6];
    #pragma unroll
    for (int j = 0; j < 6; j++) {
        int s6 = wave * 6 + j;
        if (s6 < 8) {            // A region, m in [0,64)
            int idx = s6 * 64 + lane;
            int m = idx >> 3, q = (idx & 7) ^ (m & 7);
            src[j]  = gq + (size_t)(m0 + m) * CA + q * 8;
            loff[j] = s6 * 512;
        } else {                 // B region, m in [0,128)
            int idx = (s6 - 8) * 64 + lane;
            int m = idx >> 3, q = (idx & 7) ^ (m & 7);
            src[j]  = w2T + (size_t)(n0 + m) * CA + q * 8;
            loff[j] = 4096 + (s6 - 8) * 512;
        }
    }

    f32x4 acc[2][4] = {};

    auto STAGE = [&](int t, int buf) {
        #pragma unroll
        for (int j = 0; j < 6; j++)
            ld16(&lds[buf][loff[j]], src[j] + t * 64);
    };

    STAGE(0, 0);

    #pragma unroll
    for (int t = 0; t < 3; t++) {
        asm volatile("s_waitcnt vmcnt(0)" ::: "memory");
        __builtin_amdgcn_s_barrier();
        if (t < 2) STAGE(t + 1, (t + 1) & 1);

        const short* A = &lds[t & 1][0];
        const short* B = &lds[t & 1][4096];
        #pragma unroll
        for (int kk = 0; kk < 2; kk++) {
            const int c = kk * 4 + lg;
            short8 af[2], bf[4];
            #pragma unroll
            for (int i2 = 0; i2 < 2; i2++) {
                int r = wm * 32 + i2 * 16 + lm;
                af[i2] = *(const short8*)&A[(r * 8 + (c ^ (r & 7))) * 8];
            }
            #pragma unroll
            for (int j = 0; j < 4; j++) {
                int rB = wn * 64 + j * 16 + lm;
                bf[j] = *(const short8*)&B[(rB * 8 + (c ^ (rB & 7))) * 8];
            }
            #pragma unroll
            for (int i2 = 0; i2 < 2; i2++)
                #pragma unroll
                for (int j = 0; j < 4; j++)
                    acc[i2][j] = __builtin_amdgcn_mfma_f32_16x16x32_bf16(af[i2], bf[j], acc[i2][j], 0, 0, 0);
        }
    }

    #pragma unroll
    for (int i2 = 0; i2 < 2; i2++) {
        const int row0 = m0 + wm * 32 + i2 * 16 + lg * 4;
        #pragma unroll
        for (int j = 0; j < 4; j++) {
            const int col = n0 + wn * 64 + j * 16 + lm;
            const float bias = b2[col];
            #pragma unroll
            for (int r = 0; r < 4; r++) {
                const size_t idx = (size_t)(row0 + r) * DIM + col;
                out[idx] = acc[i2][j][r] + x[idx] + bias;
            }
        }
    }
}

// ---------------------------------------------------------------------------
extern "C" void kernel_launch(void* const* d_in, const int* in_sizes, int n_in,
                              void* d_out, int out_size, void* d_ws, size_t ws_size,
                              hipStream_t stream) {
    (void)in_sizes; (void)n_in; (void)out_size; (void)ws_size;
    const float* x      = (const float*)d_in[0];
    const float* w1     = (const float*)d_in[1];
    const float* b1     = (const float*)d_in[2];
    const float* conv_w = (const float*)d_in[3];
    const float* conv_b = (const float*)d_in[4];
    const float* w2     = (const float*)d_in[5];
    const float* b2     = (const float*)d_in[6];
    float* out = (float*)d_out;

    char* ws = (char*)d_ws;
    short* g   = (short*)ws;                           // 25216*192*2 = 9,682,944 B
    short* w1T = (short*)(ws + 9682944);               // 294,912 B
    short* w2T = (short*)(ws + 9682944 + 294912);      // 294,912 B

    prep_kernel<<<(CA * DIM + 255) / 256, 256, 0, stream>>>(w1, w2, w1T, w2T);
    gemm1_fused<<<784, 256, 0, stream>>>(x, w1T, b1, conv_w, conv_b, g);
    gemm2_kernel<<<dim3(394, 6), 256, 0, stream>>>(g, w2T, b2, x, out);
}